// Round 6
// baseline (1203.731 us; speedup 1.0000x reference)
//
#include <hip/hip_runtime.h>
#include <math.h>

#define BB 8
#define NN 4096
#define MM 256
#define NT 256
#define CPT 16   /* contiguous columns per thread: thread t owns [16t, 16t+16) */

// 5*L1 - 2*IoU, float32, same op structure/order as the jax reference
__device__ __forceinline__ float cost_fn(const float4 p, const float4 t) {
  float l1 = fabsf(p.x - t.x) + fabsf(p.y - t.y) + fabsf(p.z - t.z) + fabsf(p.w - t.w);
  float ltx = fmaxf(p.x, t.x), lty = fmaxf(p.y, t.y);
  float rbx = fminf(p.z, t.z), rby = fminf(p.w, t.w);
  float wx = rbx - ltx; wx = wx > 0.f ? wx : 0.f;
  float wy = rby - lty; wy = wy > 0.f ? wy : 0.f;
  float inter = wx * wy;
  float ap = (p.z - p.x) * (p.w - p.y);
  float at = (t.z - t.x) * (t.w - t.y);
  float un = ap + at - inter;
  float iou = inter / (un + 1e-6f);
  return 5.0f * l1 - 2.0f * iou;
}

__global__ void cost_kernel(const float4* __restrict__ pred,
                            const float4* __restrict__ tgt,
                            float* __restrict__ outc) {
  int bn = blockIdx.x;
  int m = threadIdx.x;
  int b = bn >> 12;
  outc[(size_t)bn * MM + m] = cost_fn(pred[bn], tgt[b * MM + m]);
}

__global__ void costT_kernel(const float4* __restrict__ pred,
                             const float4* __restrict__ tgt,
                             float* __restrict__ costT) {
  int bm = blockIdx.x;            // b*MM + m
  int b = bm >> 8;
  float4 tb = tgt[bm];
  const float4* pb = pred + (size_t)b * NN;
  float* out = costT + (size_t)bm * NN;
  int t = threadIdx.x;
#pragma unroll
  for (int k = 0; k < CPT; ++k) {
    int n = t + k * NT;
    out[n] = cost_fn(pb[n], tb);
  }
}

// ---- cross-lane helpers -----------------------------------------------------
template <int CTRL>
__device__ __forceinline__ int dppmov(int x) {
  return __builtin_amdgcn_mov_dpp(x, CTRL, 0xF, 0xF, true);
}
template <int PAT>
__device__ __forceinline__ int swz(int x) {
  return __builtin_amdgcn_ds_swizzle(x, PAT);
}
__device__ __forceinline__ double mkdbl(int lo, int hi) {
  return __longlong_as_double(((long long)hi << 32) | (unsigned)lo);
}
// lexicographic (val, pay) min; pay has col in high bits => numpy first-min
__device__ __forceinline__ void pick(double& v, unsigned& p, double v2, unsigned p2) {
  if (v2 < v || (v2 == v && p2 < p)) { v = v2; p = p2; }
}
template <int CTRL>
__device__ __forceinline__ void bfly_dpp(double& v, unsigned& p) {
  long long bv = __double_as_longlong(v);
  int lo = (int)bv, hi = (int)(bv >> 32);
  int plo = dppmov<CTRL>(lo), phi = dppmov<CTRL>(hi), pp = dppmov<CTRL>((int)p);
  pick(v, p, mkdbl(plo, phi), (unsigned)pp);
}
template <int PAT>
__device__ __forceinline__ void bfly_swz(double& v, unsigned& p) {
  long long bv = __double_as_longlong(v);
  int lo = (int)bv, hi = (int)(bv >> 32);
  int plo = swz<PAT>(lo), phi = swz<PAT>(hi), pp = swz<PAT>((int)p);
  pick(v, p, mkdbl(plo, phi), (unsigned)pp);
}

struct LsaShared {
  double u[MM];
  double redv[2][4];
  unsigned redp[2][4];
  int r4cw[8 * MM];               // packed row4col pairs, transposed: pair p -> (p&7)*MM + p/8
  unsigned pathw[4 * MM];         // packed path bytes, transposed [q][t]
  int col4row[MM];
  float tx1[MM], ty1[MM], tx2[MM], ty2[MM];
  unsigned char sr[MM];
};

template <bool USE_T>
__global__ void __launch_bounds__(NT, 1)
lsa_kernel(const float4* __restrict__ pred, const float4* __restrict__ tgt,
           const float* __restrict__ costT,
           float* __restrict__ out_pred, float* __restrict__ out_tgt) {
  __shared__ LsaShared S;
  const int b = blockIdx.x;
  const int t = threadIdx.x;
  const int base = t * CPT;
  const int wid = t >> 6;

  float4 pbox[CPT];               // fallback path only
  if (!USE_T) {
    const float4* pb = pred + (size_t)b * NN;
#pragma unroll
    for (int k = 0; k < CPT; ++k) pbox[k] = pb[base + k];
  }
  {
    float4 tb = tgt[b * MM + t];
    S.tx1[t] = tb.x; S.ty1[t] = tb.y; S.tx2[t] = tb.z; S.ty2[t] = tb.w;
    S.u[t] = 0.0;
    S.col4row[t] = -1;
    S.sr[t] = 0;
  }
#pragma unroll
  for (int q = 0; q < 8; ++q) S.r4cw[q * MM + t] = -1;

  double v_reg[CPT];
  unsigned pay[CPT];              // (col<<9) | (row4col[col]+1)
  unsigned path_reg[CPT];
#pragma unroll
  for (int k = 0; k < CPT; ++k) {
    v_reg[k] = 0.0;
    pay[k] = ((unsigned)(base + k) << 9);
    path_reg[k] = 0;
  }
  __syncthreads();

  const float* crowT = USE_T ? (costT + (size_t)b * MM * NN) : nullptr;

  for (int cur = 0; cur < MM; ++cur) {
    double spc[CPT];
#pragma unroll
    for (int k = 0; k < CPT; ++k) spc[k] = (double)INFINITY;
    unsigned scm = 0;             // SC bitmask for owned columns
    int i = cur;
    double minval = 0.0;
    int parity = 0;
    int sink = -1;

    for (;;) {
      if (t == i) S.sr[t] = 1;
      float c[CPT];
      if (USE_T) {
        const float4* rp = reinterpret_cast<const float4*>(crowT + (size_t)i * NN + base);
        float4 c0 = rp[0], c1 = rp[1], c2 = rp[2], c3 = rp[3];
        c[0] = c0.x; c[1] = c0.y; c[2] = c0.z; c[3] = c0.w;
        c[4] = c1.x; c[5] = c1.y; c[6] = c1.z; c[7] = c1.w;
        c[8] = c2.x; c[9] = c2.y; c[10] = c2.z; c[11] = c2.w;
        c[12] = c3.x; c[13] = c3.y; c[14] = c3.z; c[15] = c3.w;
      } else {
        float4 tb = make_float4(S.tx1[i], S.ty1[i], S.tx2[i], S.ty2[i]);
#pragma unroll
        for (int k = 0; k < CPT; ++k) c[k] = cost_fn(pbox[k], tb);
      }
      double u_i = S.u[i];
      // scan: update spc/path, produce masked values for argmin
      double tv[CPT];
#pragma unroll
      for (int k = 0; k < CPT; ++k) {
        bool open = !((scm >> k) & 1u);
        // numpy op order: ((min_val + cost) - u[i]) - v[j], all f64
        double r = ((minval + (double)c[k]) - u_i) - v_reg[k];
        if (open && r < spc[k]) { spc[k] = r; path_reg[k] = (unsigned)i; }
        tv[k] = open ? spc[k] : (double)INFINITY;
      }
      // local argmin: balanced tree, left-wins-ties (== first-occurrence)
      double av[8]; unsigned ap[8];
#pragma unroll
      for (int j = 0; j < 8; ++j) {
        av[j] = tv[2 * j]; ap[j] = pay[2 * j];
        pick(av[j], ap[j], tv[2 * j + 1], pay[2 * j + 1]);
      }
      double bv[4]; unsigned bp[4];
#pragma unroll
      for (int j = 0; j < 4; ++j) {
        bv[j] = av[2 * j]; bp[j] = ap[2 * j];
        pick(bv[j], bp[j], av[2 * j + 1], ap[2 * j + 1]);
      }
      double cv0 = bv[0]; unsigned cp0 = bp[0]; pick(cv0, cp0, bv[1], bp[1]);
      double cv1 = bv[2]; unsigned cp1 = bp[2]; pick(cv1, cp1, bv[3], bp[3]);
      double bestv = cv0; unsigned bestp = cp0; pick(bestv, bestp, cv1, cp1);
      // wave butterfly: DPP for xor1/2, ds_swizzle for xor4/8/16, readlane for 32
      bfly_dpp<0xB1>(bestv, bestp);          // quad_perm [1,0,3,2] = xor1
      bfly_dpp<0x4E>(bestv, bestp);          // quad_perm [2,3,0,1] = xor2
      bfly_swz<0x101F>(bestv, bestp);        // xor4
      bfly_swz<0x201F>(bestv, bestp);        // xor8
      bfly_swz<0x401F>(bestv, bestp);        // xor16
      {
        double v0 = __shfl(bestv, 0), v32 = __shfl(bestv, 32);
        unsigned p0 = __shfl(bestp, 0), p32 = __shfl(bestp, 32);
        pick(v0, p0, v32, p32);
        bestv = v0; bestp = p0;
      }
      if ((t & 63) == 0) { S.redv[parity][wid] = bestv; S.redp[parity][wid] = bestp; }
      __syncthreads();            // the only barrier per step
      double m0 = S.redv[parity][0]; unsigned q0 = S.redp[parity][0];
      double m1 = S.redv[parity][1]; unsigned q1 = S.redp[parity][1];
      double m2 = S.redv[parity][2]; unsigned q2 = S.redp[parity][2];
      double m3 = S.redv[parity][3]; unsigned q3 = S.redp[parity][3];
      pick(m0, q0, m1, q1);
      pick(m2, q2, m3, q3);
      pick(m0, q0, m2, q2);
      parity ^= 1;
      minval = m0;
      int mj = (int)(q0 >> 9);
      int rc = (int)(q0 & 511u) - 1;        // row4col[mj], carried through the reduce
      if ((mj >> 4) == t) scm |= (1u << (mj & 15));
      if (rc < 0) { sink = mj; break; }
      i = rc;
    }

    // ---- dual updates (column-owner push; row4col injective => race-free) ----
#pragma unroll
    for (int k = 0; k < CPT; ++k) {
      int rc2 = (int)(pay[k] & 511u) - 1;
      if (rc2 >= 0 && rc2 != cur && S.sr[rc2]) S.u[rc2] += minval - spc[k];
      if ((scm >> k) & 1u) v_reg[k] -= (minval - spc[k]);
    }
    if (t == cur) S.u[t] += minval;
    // ---- publish path registers (transposed words: conflict-free) ----
#pragma unroll
    for (int q = 0; q < 4; ++q) {
      unsigned w = (path_reg[4 * q] & 255u) | ((path_reg[4 * q + 1] & 255u) << 8) |
                   ((path_reg[4 * q + 2] & 255u) << 16) | ((path_reg[4 * q + 3] & 255u) << 24);
      S.pathw[q * MM + t] = w;
    }
    __syncthreads();
    // ---- augment along alternating path (short serial walk) ----
    if (t == 0) {
      int j = sink;
      for (;;) {
        unsigned w = S.pathw[((j >> 2) & 3) * MM + (j >> 4)];
        int i2 = (int)((w >> ((j & 3) * 8)) & 255u);
        int p = j >> 1;
        int wi = (p & 7) * MM + (p >> 3);
        int old = S.r4cw[wi];
        S.r4cw[wi] = (j & 1) ? ((old & 0xFFFF) | (i2 << 16))
                             : ((old & ~0xFFFF) | (i2 & 0xFFFF));
        int tmp = S.col4row[i2];
        S.col4row[i2] = j;
        j = tmp;
        if (i2 == cur) break;
      }
    }
    __syncthreads();
    S.sr[t] = 0;
    // ---- refresh pay for owned cols (conflict-free stride-256 reads) ----
#pragma unroll
    for (int q = 0; q < 8; ++q) {
      int w = S.r4cw[q * MM + t];
      int r0 = (int)(short)(w & 0xFFFF);
      int r1 = (w >> 16);                  // arithmetic shift sign-extends
      pay[2 * q] = ((unsigned)(base + 2 * q) << 9) | (unsigned)(r0 + 1);
      pay[2 * q + 1] = ((unsigned)(base + 2 * q + 1) << 9) | (unsigned)(r1 + 1);
    }
  }

  // ---- outputs: argsort of the assignment permutation ----
  {
    int myc = S.col4row[t];
    int rank = 0;
    for (int r = 0; r < MM; ++r) rank += (S.col4row[r] < myc) ? 1 : 0;
    out_pred[(size_t)b * MM + rank] = (float)myc;
    out_tgt[(size_t)b * MM + rank] = (float)t;
  }
}

extern "C" void kernel_launch(void* const* d_in, const int* in_sizes, int n_in,
                              void* d_out, int out_size, void* d_ws, size_t ws_size,
                              hipStream_t stream) {
  const float4* pred = (const float4*)d_in[0];   // [B,N,4] f32
  const float4* tgt  = (const float4*)d_in[1];   // [B,M,4] f32

  float* outc = (float*)d_out;
  float* out_pred = outc + (size_t)BB * NN * MM;
  float* out_tgt = out_pred + (size_t)BB * MM;
  float* costT = (float*)d_ws;
  const size_t needT = (size_t)BB * MM * NN * sizeof(float);  // 33.5 MB

  cost_kernel<<<dim3(BB * NN), dim3(MM), 0, stream>>>(pred, tgt, outc);

  if (ws_size >= needT) {
    costT_kernel<<<dim3(BB * MM), dim3(NT), 0, stream>>>(pred, tgt, costT);
    lsa_kernel<true><<<dim3(BB), dim3(NT), 0, stream>>>(pred, tgt, costT, out_pred, out_tgt);
  } else {
    lsa_kernel<false><<<dim3(BB), dim3(NT), 0, stream>>>(pred, tgt, nullptr, out_pred, out_tgt);
  }
}

// Round 7
// 917.360 us; speedup vs baseline: 1.3122x; 1.3122x over previous
//
#include <hip/hip_runtime.h>
#include <math.h>

#define BB 8
#define NN 4096
#define MM 256
#define NT 256
#define CPT 16   /* contiguous columns per thread: thread t owns [16t, 16t+16) */

// 5*L1 - 2*IoU, float32, same op structure/order as the jax reference
__device__ __forceinline__ float cost_fn(const float4 p, const float4 t) {
  float l1 = fabsf(p.x - t.x) + fabsf(p.y - t.y) + fabsf(p.z - t.z) + fabsf(p.w - t.w);
  float ltx = fmaxf(p.x, t.x), lty = fmaxf(p.y, t.y);
  float rbx = fminf(p.z, t.z), rby = fminf(p.w, t.w);
  float wx = rbx - ltx; wx = wx > 0.f ? wx : 0.f;
  float wy = rby - lty; wy = wy > 0.f ? wy : 0.f;
  float inter = wx * wy;
  float ap = (p.z - p.x) * (p.w - p.y);
  float at = (t.z - t.x) * (t.w - t.y);
  float un = ap + at - inter;
  float iou = inter / (un + 1e-6f);
  return 5.0f * l1 - 2.0f * iou;
}

__global__ void cost_kernel(const float4* __restrict__ pred,
                            const float4* __restrict__ tgt,
                            float* __restrict__ outc) {
  int bn = blockIdx.x;
  int m = threadIdx.x;
  int b = bn >> 12;
  outc[(size_t)bn * MM + m] = cost_fn(pred[bn], tgt[b * MM + m]);
}

__global__ void costT_kernel(const float4* __restrict__ pred,
                             const float4* __restrict__ tgt,
                             float* __restrict__ costT) {
  int bm = blockIdx.x;            // b*MM + m
  int b = bm >> 8;
  float4 tb = tgt[bm];
  const float4* pb = pred + (size_t)b * NN;
  float* out = costT + (size_t)bm * NN;
  int t = threadIdx.x;
#pragma unroll
  for (int k = 0; k < CPT; ++k) {
    int n = t + k * NT;
    out[n] = cost_fn(pb[n], tb);
  }
}

// lexicographic (val, pay) min; pay has col in high bits => numpy first-min
__device__ __forceinline__ void pick(double& v, unsigned& p, double v2, unsigned p2) {
  if (v2 < v || (v2 == v && p2 < p)) { v = v2; p = p2; }
}

struct LsaShared {
  double u[MM];
  double redv[2][4];
  unsigned redp[2][4];
  short row4col[NN];              // col -> assigned row, -1 free (plain, t0-writable)
  unsigned pathw[4 * MM];         // packed path bytes, transposed [q][t]
  int col4row[MM];
  float tx1[MM], ty1[MM], tx2[MM], ty2[MM];
};

template <bool USE_T>
__global__ void __launch_bounds__(NT, 1)
lsa_kernel(const float4* __restrict__ pred, const float4* __restrict__ tgt,
           const float* __restrict__ costT,
           float* __restrict__ out_pred, float* __restrict__ out_tgt) {
  __shared__ LsaShared S;
  const int b = blockIdx.x;
  const int t = threadIdx.x;
  const int base = t * CPT;
  const int wid = t >> 6;

  float4 pbox[CPT];               // fallback path only
  if (!USE_T) {
    const float4* pb = pred + (size_t)b * NN;
#pragma unroll
    for (int k = 0; k < CPT; ++k) pbox[k] = pb[base + k];
  }
  {
    float4 tb = tgt[b * MM + t];
    S.tx1[t] = tb.x; S.ty1[t] = tb.y; S.tx2[t] = tb.z; S.ty2[t] = tb.w;
    S.u[t] = 0.0;
    S.col4row[t] = -1;
  }
  int* r4c_i = reinterpret_cast<int*>(S.row4col);
#pragma unroll
  for (int q = 0; q < 8; ++q) r4c_i[t * 8 + q] = (int)0xFFFFFFFF;

  double v_reg[CPT];
  unsigned pay[CPT];              // (col<<9) | (row4col[col]+1)
  unsigned path_reg[CPT];
#pragma unroll
  for (int k = 0; k < CPT; ++k) {
    v_reg[k] = 0.0;
    pay[k] = ((unsigned)(base + k) << 9);
    path_reg[k] = 0;
  }
  __syncthreads();

  const float* crowT = USE_T ? (costT + (size_t)b * MM * NN) : nullptr;

  // persistent prefetch cache: cost row `pre_row` (costT immutable => never stale)
  int pre_row = -1;
  float4 cp0, cp1, cp2, cp3;

  for (int cur = 0; cur < MM; ++cur) {
    double spc[CPT];
#pragma unroll
    for (int k = 0; k < CPT; ++k) spc[k] = (double)INFINITY;
    unsigned scm = 0;             // SC bitmask for owned columns
    int i = cur;
    double minval = 0.0;
    int parity = 0;
    int sink = -1;
    int prow = -1;                // predicted next row (from runner-up)

    for (;;) {
      // ---- acquire cost row i ----
      float c[CPT];
      if (USE_T) {
        float4 q0, q1, q2, q3;
        if (i == pre_row) {
          q0 = cp0; q1 = cp1; q2 = cp2; q3 = cp3;
        } else {
          const float4* rp = reinterpret_cast<const float4*>(crowT + (size_t)i * NN + base);
          q0 = rp[0]; q1 = rp[1]; q2 = rp[2]; q3 = rp[3];
        }
        // prefetch predicted next row (overlaps scan+butterfly+barrier)
        if (prow >= 0 && prow != i && prow != pre_row) {
          const float4* pp = reinterpret_cast<const float4*>(crowT + (size_t)prow * NN + base);
          cp0 = pp[0]; cp1 = pp[1]; cp2 = pp[2]; cp3 = pp[3];
          pre_row = prow;
        }
        c[0] = q0.x; c[1] = q0.y; c[2] = q0.z; c[3] = q0.w;
        c[4] = q1.x; c[5] = q1.y; c[6] = q1.z; c[7] = q1.w;
        c[8] = q2.x; c[9] = q2.y; c[10] = q2.z; c[11] = q2.w;
        c[12] = q3.x; c[13] = q3.y; c[14] = q3.z; c[15] = q3.w;
      } else {
        float4 tb = make_float4(S.tx1[i], S.ty1[i], S.tx2[i], S.ty2[i]);
#pragma unroll
        for (int k = 0; k < CPT; ++k) c[k] = cost_fn(pbox[k], tb);
      }
      double u_i = S.u[i];
      // ---- scan: update spc/path, running local argmin (k asc => first-min) ----
      double bestv = (double)INFINITY;
      unsigned bestp = 0xFFFFFFFFu;
#pragma unroll
      for (int k = 0; k < CPT; ++k) {
        bool open = !((scm >> k) & 1u);
        // numpy op order: ((min_val + cost) - u[i]) - v[j], all f64
        double r = ((minval + (double)c[k]) - u_i) - v_reg[k];
        if (open && r < spc[k]) { spc[k] = r; path_reg[k] = (unsigned)i; }
        if (open && spc[k] < bestv) { bestv = spc[k]; bestp = pay[k]; }
      }
      // ---- wave butterfly (lexicographic (val, pay)) ----
#pragma unroll
      for (int off = 1; off <= 32; off <<= 1) {
        double ov = __shfl_xor(bestv, off);
        unsigned op = __shfl_xor(bestp, off);
        pick(bestv, bestp, ov, op);
      }
      if ((t & 63) == 0) { S.redv[parity][wid] = bestv; S.redp[parity][wid] = bestp; }
      __syncthreads();            // the only barrier per step
      // ---- tournament merge: exact winner + runner-up predictor ----
      double a0 = S.redv[parity][0], a1 = S.redv[parity][1];
      double a2 = S.redv[parity][2], a3 = S.redv[parity][3];
      unsigned b0 = S.redp[parity][0], b1 = S.redp[parity][1];
      unsigned b2 = S.redp[parity][2], b3 = S.redp[parity][3];
      parity ^= 1;
      double lo0 = a0, hi0 = a1; unsigned lp0 = b0, hp0 = b1;
      if (a1 < a0 || (a1 == a0 && b1 < b0)) { lo0 = a1; lp0 = b1; hi0 = a0; hp0 = b0; }
      double lo1 = a2, hi1 = a3; unsigned lp1 = b2, hp1 = b3;
      if (a3 < a2 || (a3 == a2 && b3 < b2)) { lo1 = a3; lp1 = b3; hi1 = a2; hp1 = b2; }
      double wv, rv; unsigned wp, rp;
      if (lo1 < lo0 || (lo1 == lo0 && lp1 < lp0)) {
        wv = lo1; wp = lp1; rv = lo0; rp = lp0; pick(rv, rp, hi1, hp1);
      } else {
        wv = lo0; wp = lp0; rv = lo1; rp = lp1; pick(rv, rp, hi0, hp0);
      }
      minval = wv;
      int mj = (int)(wp >> 9);
      int rc = (int)(wp & 511u) - 1;        // row4col[mj], carried through the reduce
      prow = (int)(rp & 511u) - 1;          // runner-up's row = predicted next
      if ((mj >> 4) == t) scm |= (1u << (mj & 15));
      if (rc < 0) { sink = mj; break; }
      i = rc;
    }

    // ---- dual updates (SR\{cur} == {row4col[j] : j in SC, matched} bijection) ----
#pragma unroll
    for (int k = 0; k < CPT; ++k) {
      if ((scm >> k) & 1u) {
        double d = minval - spc[k];
        int rc2 = (int)(pay[k] & 511u) - 1;   // pre-augment row4col
        if (rc2 >= 0) S.u[rc2] += d;          // distinct rc2 => race-free; never cur
        v_reg[k] -= d;
      }
    }
    if (t == cur) S.u[t] += minval;
    // ---- publish path registers (transposed words: conflict-free) ----
#pragma unroll
    for (int q = 0; q < 4; ++q) {
      unsigned w = (path_reg[4 * q] & 255u) | ((path_reg[4 * q + 1] & 255u) << 8) |
                   ((path_reg[4 * q + 2] & 255u) << 16) | ((path_reg[4 * q + 3] & 255u) << 24);
      S.pathw[q * MM + t] = w;
    }
    __syncthreads();
    // ---- augment along alternating path (short serial walk, direct short writes) ----
    if (t == 0) {
      int j = sink;
      for (;;) {
        unsigned w = S.pathw[((j >> 2) & 3) * MM + (j >> 4)];
        int i2 = (int)((w >> ((j & 3) * 8)) & 255u);
        S.row4col[j] = (short)i2;
        int tmp = S.col4row[i2];
        S.col4row[i2] = j;
        j = tmp;
        if (i2 == cur) break;
      }
    }
    __syncthreads();
    // ---- refresh pay for owned cols (8 packed int reads, once per augmentation) ----
#pragma unroll
    for (int q = 0; q < 8; ++q) {
      int w = r4c_i[t * 8 + q];
      int r0 = (int)(short)(w & 0xFFFF);
      int r1 = (w >> 16);                  // arithmetic shift sign-extends
      pay[2 * q] = ((unsigned)(base + 2 * q) << 9) | (unsigned)(r0 + 1);
      pay[2 * q + 1] = ((unsigned)(base + 2 * q + 1) << 9) | (unsigned)(r1 + 1);
    }
  }

  // ---- outputs: argsort of the assignment permutation ----
  {
    int myc = S.col4row[t];
    int rank = 0;
    for (int r = 0; r < MM; ++r) rank += (S.col4row[r] < myc) ? 1 : 0;
    out_pred[(size_t)b * MM + rank] = (float)myc;
    out_tgt[(size_t)b * MM + rank] = (float)t;
  }
}

extern "C" void kernel_launch(void* const* d_in, const int* in_sizes, int n_in,
                              void* d_out, int out_size, void* d_ws, size_t ws_size,
                              hipStream_t stream) {
  const float4* pred = (const float4*)d_in[0];   // [B,N,4] f32
  const float4* tgt  = (const float4*)d_in[1];   // [B,M,4] f32

  float* outc = (float*)d_out;
  float* out_pred = outc + (size_t)BB * NN * MM;
  float* out_tgt = out_pred + (size_t)BB * MM;
  float* costT = (float*)d_ws;
  const size_t needT = (size_t)BB * MM * NN * sizeof(float);  // 33.5 MB

  cost_kernel<<<dim3(BB * NN), dim3(MM), 0, stream>>>(pred, tgt, outc);

  if (ws_size >= needT) {
    costT_kernel<<<dim3(BB * MM), dim3(NT), 0, stream>>>(pred, tgt, costT);
    lsa_kernel<true><<<dim3(BB), dim3(NT), 0, stream>>>(pred, tgt, costT, out_pred, out_tgt);
  } else {
    lsa_kernel<false><<<dim3(BB), dim3(NT), 0, stream>>>(pred, tgt, nullptr, out_pred, out_tgt);
  }
}